// Round 15
// baseline (180.137 us; speedup 1.0000x reference)
//
#include <hip/hip_runtime.h>
#include <hip/hip_bf16.h>

#define NN 50000
#define NE 800000
#define DD 128
#define BN_EPS 1e-5f
#define SCAN_G 98    // 98*512 = 50176 >= NN
#define E4 200000    // NE/4

typedef unsigned short ushort_t;
typedef unsigned int uint_t;
typedef __attribute__((ext_vector_type(8))) short short8v;   // 8 x bf16 (4 VGPR)
typedef __attribute__((ext_vector_type(4))) float f32x4;

__device__ __forceinline__ float b2f(ushort_t u) {
    union { uint_t i; float f; } v; v.i = ((uint_t)u) << 16; return v.f;
}
__device__ __forceinline__ ushort_t f2b(float f) {
    uint_t u = __float_as_uint(f);
    u += 0x7FFFu + ((u >> 16) & 1u);   // RNE
    return (ushort_t)(u >> 16);
}
__device__ __forceinline__ void atomAdd(float* p, float v) { unsafeAtomicAdd(p, v); }

// ---------- graph prep + feat->bf16 (fused) ----------
// 4 edges/thread: 4 independent returning atomics in flight per lane.
// cnt_pad: one counter per 64B line (dst<<4).
__global__ void epos_prep(const int4* __restrict__ dst4, int* __restrict__ cnt_pad,
                          int4* __restrict__ epos4,
                          const float4* __restrict__ fp, ushort4* __restrict__ op) {
    int e4 = blockIdx.x * 256 + threadIdx.x;     // 782 blocks covers 200192 >= E4
    if (e4 >= E4) return;
    // convert 8 float4 -> 8 ushort4, coalesced streams at k*E4 + e4
    #pragma unroll
    for (int k = 0; k < 8; ++k) {
        int i = k * E4 + e4;
        float4 v = fp[i];
        ushort4 o = { f2b(v.x), f2b(v.y), f2b(v.z), f2b(v.w) };
        op[i] = o;
    }
    int4 d = dst4[e4];
    int p0 = atomicAdd(&cnt_pad[d.x << 4], 1);
    int p1 = atomicAdd(&cnt_pad[d.y << 4], 1);
    int p2 = atomicAdd(&cnt_pad[d.z << 4], 1);
    int p3 = atomicAdd(&cnt_pad[d.w << 4], 1);
    epos4[e4] = make_int4(p0, p1, p2, p3);
}

// pass 1: per-block (512 elems) sums; also emits norm = rsqrt(max(deg,1))
__global__ __launch_bounds__(512) void scan_part(const int* __restrict__ cnt_pad,
                                                 int* __restrict__ part,
                                                 float* __restrict__ norm) {
    int i = blockIdx.x * 512 + threadIdx.x;
    int v = (i < NN) ? cnt_pad[i << 4] : 0;
    if (i < NN) norm[i] = rsqrtf((float)max(v, 1));
    int s = v;
    #pragma unroll
    for (int k = 1; k < 64; k <<= 1) s += __shfl_xor(s, k);
    __shared__ int wsum[8];
    if ((threadIdx.x & 63) == 0) wsum[threadIdx.x >> 6] = s;
    __syncthreads();
    if (threadIdx.x == 0) {
        int t = 0;
        #pragma unroll
        for (int k = 0; k < 8; ++k) t += wsum[k];
        part[blockIdx.x] = t;
    }
}

// pass 2 (blocks < SCAN_G): block-local exclusive scan + in-block base.
// blocks >= SCAN_G: build WcT (128x384 bf16): k<128: W1-W3; k<256: -W2; else 2*W3.
__global__ __launch_bounds__(512) void scan_final(const int* __restrict__ cnt_pad,
                                                  const int* __restrict__ part,
                                                  int* __restrict__ off,
                                                  const float* __restrict__ W1,
                                                  const float* __restrict__ W2,
                                                  const float* __restrict__ W3,
                                                  ushort_t* __restrict__ wcT) {
    if (blockIdx.x >= SCAN_G) {
        int i = (blockIdx.x - SCAN_G) * 512 + threadIdx.x;   // 96*512 = 49152 = 128*384
        int d = i / 384, k = i % 384;
        float v;
        if (k < 128)      v = W1[k * DD + d] - W3[k * DD + d];
        else if (k < 256) v = -W2[(k - 128) * DD + d];
        else              v = 2.0f * W3[(k - 256) * DD + d];
        wcT[i] = f2b(v);
        return;
    }
    __shared__ int wsum[8];
    __shared__ int sbase;
    int t = threadIdx.x;
    int lane = t & 63, wv = t >> 6;

    int p = (t < blockIdx.x && t < SCAN_G) ? part[t] : 0;
    #pragma unroll
    for (int s = 1; s < 64; s <<= 1) p += __shfl_xor(p, s);
    if (lane == 0) wsum[wv] = p;
    __syncthreads();
    if (t == 0) {
        int b = 0;
        #pragma unroll
        for (int k = 0; k < 8; ++k) b += wsum[k];
        sbase = b;
    }
    __syncthreads();

    int i = blockIdx.x * 512 + t;
    int v = (i < NN) ? cnt_pad[i << 4] : 0;
    int incl = v;
    #pragma unroll
    for (int s = 1; s < 64; s <<= 1) {
        int u = __shfl_up(incl, s);
        if (lane >= s) incl += u;
    }
    __syncthreads();
    if (lane == 63) wsum[wv] = incl;
    __syncthreads();
    int woff = 0;
    for (int k = 0; k < wv; ++k) woff += wsum[k];
    int excl = sbase + woff + incl - v;
    if (i < NN) off[i] = excl;
    if (blockIdx.x == 0 && t == 0) off[NN] = NE;
}

// csr[off[dst]+epos] = (src, bits(norm[src])) — atomic-free, 4 edges/thread
__global__ void fill_kernel(const int4* __restrict__ src4, const int4* __restrict__ dst4,
                            const int4* __restrict__ epos4, const int* __restrict__ off,
                            const float* __restrict__ norm, int2* __restrict__ csr) {
    int e4 = blockIdx.x * 256 + threadIdx.x;
    if (e4 >= E4) return;
    int4 s = src4[e4];
    int4 d = dst4[e4];
    int4 p = epos4[e4];
    int o0 = off[d.x], o1 = off[d.y], o2 = off[d.z], o3 = off[d.w];
    float n0 = norm[s.x], n1 = norm[s.y], n2 = norm[s.z], n3 = norm[s.w];
    csr[o0 + p.x] = make_int2(s.x, __float_as_int(n0));
    csr[o1 + p.y] = make_int2(s.y, __float_as_int(n1));
    csr[o2 + p.z] = make_int2(s.z, __float_as_int(n2));
    csr[o3 + p.w] = make_int2(s.w, __float_as_int(n3));
}

// ---------- message passing (bf16 in, bf16 out) ----------
// QUARTER-WAVE (16 lanes) per NODE; lane covers 8 cols (uint4 = 16B).
// 8-deep unroll => 8 independent row loads per group, 32 per wave.
__global__ __launch_bounds__(256) void gather_bf(const ushort_t* __restrict__ x,
                                                 const float* __restrict__ norm,
                                                 const int* __restrict__ off,
                                                 const int2* __restrict__ csr,
                                                 ushort_t* __restrict__ out) {
    int g = (blockIdx.x << 4) | (threadIdx.x >> 4);   // node id; 3125*16 = 50000
    int l4 = threadIdx.x & 15;
    int jb = off[g], je = off[g + 1];
    const uint4* xp = reinterpret_cast<const uint4*>(x);   // row = 16 x uint4
    float a0 = 0.f, a1 = 0.f, a2 = 0.f, a3 = 0.f;
    float a4 = 0.f, a5 = 0.f, a6 = 0.f, a7 = 0.f;

#define ACC(cc, vv)                                                  \
    {                                                                \
        float n_ = __int_as_float(cc.y);                             \
        a0 = fmaf(n_, b2f((ushort_t)(vv.x)), a0);                    \
        a1 = fmaf(n_, b2f((ushort_t)(vv.x >> 16)), a1);              \
        a2 = fmaf(n_, b2f((ushort_t)(vv.y)), a2);                    \
        a3 = fmaf(n_, b2f((ushort_t)(vv.y >> 16)), a3);              \
        a4 = fmaf(n_, b2f((ushort_t)(vv.z)), a4);                    \
        a5 = fmaf(n_, b2f((ushort_t)(vv.z >> 16)), a5);              \
        a6 = fmaf(n_, b2f((ushort_t)(vv.w)), a6);                    \
        a7 = fmaf(n_, b2f((ushort_t)(vv.w >> 16)), a7);              \
    }

    int j = jb;
    for (; j + 8 <= je; j += 8) {
        int2 c0 = csr[j + 0];
        int2 c1 = csr[j + 1];
        int2 c2 = csr[j + 2];
        int2 c3 = csr[j + 3];
        int2 c4 = csr[j + 4];
        int2 c5 = csr[j + 5];
        int2 c6 = csr[j + 6];
        int2 c7 = csr[j + 7];
        uint4 v0 = xp[(size_t)c0.x * 16 + l4];
        uint4 v1 = xp[(size_t)c1.x * 16 + l4];
        uint4 v2 = xp[(size_t)c2.x * 16 + l4];
        uint4 v3 = xp[(size_t)c3.x * 16 + l4];
        uint4 v4 = xp[(size_t)c4.x * 16 + l4];
        uint4 v5 = xp[(size_t)c5.x * 16 + l4];
        uint4 v6 = xp[(size_t)c6.x * 16 + l4];
        uint4 v7 = xp[(size_t)c7.x * 16 + l4];
        ACC(c0, v0); ACC(c1, v1); ACC(c2, v2); ACC(c3, v3);
        ACC(c4, v4); ACC(c5, v5); ACC(c6, v6); ACC(c7, v7);
    }
    for (; j + 4 <= je; j += 4) {
        int2 c0 = csr[j + 0];
        int2 c1 = csr[j + 1];
        int2 c2 = csr[j + 2];
        int2 c3 = csr[j + 3];
        uint4 v0 = xp[(size_t)c0.x * 16 + l4];
        uint4 v1 = xp[(size_t)c1.x * 16 + l4];
        uint4 v2 = xp[(size_t)c2.x * 16 + l4];
        uint4 v3 = xp[(size_t)c3.x * 16 + l4];
        ACC(c0, v0); ACC(c1, v1); ACC(c2, v2); ACC(c3, v3);
    }
    for (; j < je; ++j) {
        int2 c = csr[j];
        uint4 v = xp[(size_t)c.x * 16 + l4];
        ACC(c, v);
    }
#undef ACC

    float nd = norm[g];
    uint4 o;
    o.x = (uint_t)f2b(nd * a0) | ((uint_t)f2b(nd * a1) << 16);
    o.y = (uint_t)f2b(nd * a2) | ((uint_t)f2b(nd * a3) << 16);
    o.z = (uint_t)f2b(nd * a4) | ((uint_t)f2b(nd * a5) << 16);
    o.w = (uint_t)f2b(nd * a6) | ((uint_t)f2b(nd * a7) << 16);
    reinterpret_cast<uint4*>(out)[(size_t)g * 16 + l4] = o;
}

// ---------- MFMA GEMM + BN partials ----------
// 128-row blocks, 4 waves; wave owns 32 rows x 128 cols (2 row-groups).
__global__ __launch_bounds__(256) void gemm_bn(
    const ushort_t* __restrict__ feat_bf, const ushort_t* __restrict__ ax_bf,
    const ushort_t* __restrict__ ax2_bf, const ushort_t* __restrict__ wcT,
    const float* __restrict__ bias, const float* __restrict__ snorm,
    ushort_t* __restrict__ t_out, float* __restrict__ gsums, float* __restrict__ gsq)
{
    __shared__ ushort_t As[128 * 128];   // 32 KB, XOR-swizzled
    __shared__ ushort_t Bs[128 * 128];   // 32 KB, XOR-swizzled
    int tid = threadIdx.x;
    int w = tid >> 6, lane = tid & 63;
    int row0 = blockIdx.x * 128;

    f32x4 acc[2][8] = {};

    #pragma unroll
    for (int kt = 0; kt < 3; ++kt) {
        const ushort_t* S = (kt == 0) ? feat_bf : (kt == 1) ? ax_bf : ax2_bf;
        __syncthreads();
        {
            int r = tid >> 1, hh = tid & 1;
            int grow = min(row0 + r, NN - 1);
            const char* gsrc = (const char*)(S + grow * DD);
            char* dbase = (char*)As + r * 256;
            int sw = (r & 7) << 4;
            #pragma unroll
            for (int c = 0; c < 8; ++c) {
                int cb = hh * 128 + c * 16;
                *(short8v*)(dbase + (cb ^ sw)) = *(const short8v*)(gsrc + cb);
            }
        }
        {
            int cidx = tid >> 1, hh = tid & 1;
            const char* gsrc = (const char*)(wcT + cidx * 384 + kt * 128);
            char* dbase = (char*)Bs + cidx * 256;
            int sw = (cidx & 7) << 4;
            #pragma unroll
            for (int c = 0; c < 8; ++c) {
                int cb = hh * 128 + c * 16;
                *(short8v*)(dbase + (cb ^ sw)) = *(const short8v*)(gsrc + cb);
            }
        }
        __syncthreads();
        int l15 = lane & 15;
        int r0a = w * 32 + l15;
        int r1a = r0a + 16;
        #pragma unroll
        for (int ks = 0; ks < 4; ++ks) {
            int kb = ks * 64 + ((lane >> 4) << 4);
            short8v a0 = *(const short8v*)((const char*)As + r0a * 256 + (kb ^ ((r0a & 7) << 4)));
            short8v a1 = *(const short8v*)((const char*)As + r1a * 256 + (kb ^ ((r1a & 7) << 4)));
            #pragma unroll
            for (int cf = 0; cf < 8; ++cf) {
                int col = cf * 16 + l15;
                short8v b = *(const short8v*)((const char*)Bs + col * 256 + (kb ^ ((col & 7) << 4)));
                acc[0][cf] = __builtin_amdgcn_mfma_f32_16x16x32_bf16(a0, b, acc[0][cf], 0, 0, 0);
                acc[1][cf] = __builtin_amdgcn_mfma_f32_16x16x32_bf16(a1, b, acc[1][cf], 0, 0, 0);
            }
        }
    }

    int q = lane >> 4, c0 = lane & 15;
    float s1[8], s2[8];
    #pragma unroll
    for (int cf = 0; cf < 8; ++cf) { s1[cf] = 0.f; s2[cf] = 0.f; }

    #pragma unroll
    for (int g = 0; g < 2; ++g) {
        int rbase = row0 + w * 32 + g * 16 + q * 4;
        float sn[4];
        #pragma unroll
        for (int i = 0; i < 4; ++i) sn[i] = (rbase + i < NN) ? snorm[rbase + i] : 0.f;
        #pragma unroll
        for (int cf = 0; cf < 8; ++cf) {
            int col = cf * 16 + c0;
            float bc = bias[col];
            #pragma unroll
            for (int i = 0; i < 4; ++i) {
                int row = rbase + i;
                if (row < NN) {
                    float t = (acc[g][cf][i] + bc) * sn[i];
                    t_out[row * DD + col] = f2b(t);
                    s1[cf] += t; s2[cf] += t * t;
                }
            }
        }
    }
    #pragma unroll
    for (int cf = 0; cf < 8; ++cf) {
        s1[cf] += __shfl_xor(s1[cf], 16); s1[cf] += __shfl_xor(s1[cf], 32);
        s2[cf] += __shfl_xor(s2[cf], 16); s2[cf] += __shfl_xor(s2[cf], 32);
    }
    if (q == 0) {
        int slot = (blockIdx.x & 31) * DD;
        #pragma unroll
        for (int cf = 0; cf < 8; ++cf) {
            atomAdd(&gsums[slot + cf * 16 + c0], s1[cf]);
            atomAdd(&gsq[slot + cf * 16 + c0], s2[cf]);
        }
    }
}

__global__ void bn_finalize(const float* __restrict__ gsums, const float* __restrict__ gsq,
                            const float* __restrict__ gamma,
                            const float* __restrict__ beta,
                            float* __restrict__ scale, float* __restrict__ shift) {
    int d = threadIdx.x;  // 128
    float s1 = 0.f, s2 = 0.f;
    for (int c = 0; c < 32; ++c) { s1 += gsums[c * DD + d]; s2 += gsq[c * DD + d]; }
    float mean = s1 / (float)NN;
    float var  = s2 / (float)NN - mean * mean;
    float sc = gamma[d] * rsqrtf(var + BN_EPS);
    scale[d] = sc;
    shift[d] = beta[d] - mean * sc;
}

// out = feat_bf + relu(t*scale + shift)   (both bf16 inputs, f32 out)
__global__ void epilogue(const ushort_t* __restrict__ t, const ushort_t* __restrict__ featb,
                         const float* __restrict__ scale, const float* __restrict__ shift,
                         float* __restrict__ out) {
    int i = blockIdx.x * 256 + threadIdx.x;
    if (i >= NN * DD / 4) return;
    int d0 = (i << 2) & 127;
    ushort4 tv = reinterpret_cast<const ushort4*>(t)[i];
    ushort4 fv = reinterpret_cast<const ushort4*>(featb)[i];
    float4 o;
    o.x = b2f(fv.x) + fmaxf(b2f(tv.x) * scale[d0 + 0] + shift[d0 + 0], 0.f);
    o.y = b2f(fv.y) + fmaxf(b2f(tv.y) * scale[d0 + 1] + shift[d0 + 1], 0.f);
    o.z = b2f(fv.z) + fmaxf(b2f(tv.z) * scale[d0 + 2] + shift[d0 + 2], 0.f);
    o.w = b2f(fv.w) + fmaxf(b2f(tv.w) * scale[d0 + 3] + shift[d0 + 3], 0.f);
    reinterpret_cast<float4*>(out)[i] = o;
}

extern "C" void kernel_launch(void* const* d_in, const int* in_sizes, int n_in,
                              void* d_out, int out_size, void* d_ws, size_t ws_size,
                              hipStream_t stream) {
    const float* feat  = (const float*)d_in[0];
    const float* snorm = (const float*)d_in[1];
    const float* W1    = (const float*)d_in[2];
    const float* W2    = (const float*)d_in[3];
    const float* W3    = (const float*)d_in[4];
    const float* bias  = (const float*)d_in[5];
    const float* gamma = (const float*)d_in[6];
    const float* beta  = (const float*)d_in[7];
    const int* esrc = (const int*)d_in[8];
    const int* edst = (const int*)d_in[9];
    float* out = (float*)d_out;

    char* ws = (char*)d_ws;
    ushort_t* t_bf    = (ushort_t*)(ws);                 // 12,800,000 (gemm output)
    int*      epos    = (int*)     (ws);                 //  3,200,000 ALIAS of t_bf
                                                         //  (epos dead before gemm_bn runs)
    ushort_t* feat_bf = (ushort_t*)(ws + 12800000);      // 12,800,000
    ushort_t* ax_bf   = (ushort_t*)(ws + 25600000);      // 12,800,000
    ushort_t* ax2_bf  = (ushort_t*)(ws + 38400000);      // 12,800,000
    int*      cnt_pad = (int*)     (ws + 38400000);      //  3,200,000 ALIAS of ax2_bf
                                                         //  (cnt_pad dead before gather#2 writes ax2_bf)
    int2*     csr     = (int2*)    (ws + 51200000);      //  6,400,000 (src, norm bits)
    float*    norm    = (float*)   (ws + 57600000);      //    200,000
    float*    gsums   = (float*)   (ws + 58000000);      //     16,384
    float*    gsq     = (float*)   (ws + 58016384);      //     16,384
    int*      off     = (int*)     (ws + 58032768);      //    200,064
    int*      part    = (int*)     (ws + 58232832);      //        512
    float*    scale   = (float*)   (ws + 58233856);      //        512
    float*    shift   = (float*)   (ws + 58234368);      //        512
    ushort_t* wcT     = (ushort_t*)(ws + 58234880);      //     98,304 (end 58,333,184)

    hipMemsetAsync(ws + 38400000, 0, 3200000, stream);   // cnt_pad (1 counter / 64B line)
    hipMemsetAsync(ws + 58000000, 0, 32768, stream);     // gsums, gsq

    epos_prep  <<<782, 256, 0, stream>>>((const int4*)edst, cnt_pad, (int4*)epos,
                                         (const float4*)feat, (ushort4*)feat_bf);
    scan_part  <<<SCAN_G, 512, 0, stream>>>(cnt_pad, part, norm);
    scan_final <<<SCAN_G + 96, 512, 0, stream>>>(cnt_pad, part, off, W1, W2, W3, wcT);
    fill_kernel<<<782, 256, 0, stream>>>((const int4*)esrc, (const int4*)edst,
                                         (const int4*)epos, off, norm, csr);

    gather_bf<<<3125, 256, 0, stream>>>(feat_bf, norm, off, csr, ax_bf);
    gather_bf<<<3125, 256, 0, stream>>>(ax_bf,   norm, off, csr, ax2_bf);

    gemm_bn<<<391, 256, 0, stream>>>(feat_bf, ax_bf, ax2_bf, wcT, bias, snorm,
                                     t_bf, gsums, gsq);
    bn_finalize<<<1, 128, 0, stream>>>(gsums, gsq, gamma, beta, scale, shift);
    epilogue   <<<6250, 256, 0, stream>>>(t_bf, feat_bf, scale, shift, out);
}

// Round 16
// 165.343 us; speedup vs baseline: 1.0895x; 1.0895x over previous
//
#include <hip/hip_runtime.h>
#include <hip/hip_bf16.h>

#define NN 50000
#define NE 800000
#define DD 128
#define BN_EPS 1e-5f
#define SCAN_G 98    // 98*512 = 50176 >= NN

typedef unsigned short ushort_t;
typedef unsigned int uint_t;
typedef __attribute__((ext_vector_type(8))) short short8v;   // 8 x bf16 (4 VGPR)
typedef __attribute__((ext_vector_type(4))) float f32x4;

__device__ __forceinline__ float b2f(ushort_t u) {
    union { uint_t i; float f; } v; v.i = ((uint_t)u) << 16; return v.f;
}
__device__ __forceinline__ ushort_t f2b(float f) {
    uint_t u = __float_as_uint(f);
    u += 0x7FFFu + ((u >> 16) & 1u);   // RNE
    return (ushort_t)(u >> 16);
}
__device__ __forceinline__ void atomAdd(float* p, float v) { unsafeAtomicAdd(p, v); }

// ---------- graph prep + feat->bf16 (fused) ----------
// epos[e] = position of edge e within its dst bucket; cnt ends as deg.
// Block 0 also zeros gsums/gsq (32 KB) — drops one memset dispatch.
__global__ void epos_prep(const int* __restrict__ dst, int* __restrict__ cnt,
                          int* __restrict__ epos,
                          const float* __restrict__ feat, ushort_t* __restrict__ feat_bf,
                          float4* __restrict__ gz) {
    int e = blockIdx.x * 256 + threadIdx.x;      // 3125*256 = 800000 exactly
    if (blockIdx.x == 0) {
        float4 z = make_float4(0.f, 0.f, 0.f, 0.f);
        #pragma unroll
        for (int k = 0; k < 8; ++k) gz[threadIdx.x + k * 256] = z;   // 32768 B
    }
    {
        const float4* fp = reinterpret_cast<const float4*>(feat);
        ushort4* op = reinterpret_cast<ushort4*>(feat_bf);
        int i = e << 1;                          // 2 float4 per thread, 1.6M total
        float4 v0 = fp[i], v1 = fp[i + 1];
        ushort4 o0 = { f2b(v0.x), f2b(v0.y), f2b(v0.z), f2b(v0.w) };
        ushort4 o1 = { f2b(v1.x), f2b(v1.y), f2b(v1.z), f2b(v1.w) };
        op[i] = o0; op[i + 1] = o1;
    }
    epos[e] = __hip_atomic_fetch_add(&cnt[dst[e]], 1,
                                     __ATOMIC_RELAXED, __HIP_MEMORY_SCOPE_AGENT);
}

// pass 1: per-block (512 elems) sums; also emits norm = rsqrt(max(deg,1))
__global__ __launch_bounds__(512) void scan_part(const int* __restrict__ cnt,
                                                 int* __restrict__ part,
                                                 float* __restrict__ norm) {
    int i = blockIdx.x * 512 + threadIdx.x;
    int v = (i < NN) ? cnt[i] : 0;
    if (i < NN) norm[i] = rsqrtf((float)max(v, 1));
    int s = v;
    #pragma unroll
    for (int k = 1; k < 64; k <<= 1) s += __shfl_xor(s, k);
    __shared__ int wsum[8];
    if ((threadIdx.x & 63) == 0) wsum[threadIdx.x >> 6] = s;
    __syncthreads();
    if (threadIdx.x == 0) {
        int t = 0;
        #pragma unroll
        for (int k = 0; k < 8; ++k) t += wsum[k];
        part[blockIdx.x] = t;
    }
}

// pass 2 (blocks < SCAN_G): block-local exclusive scan + in-block base.
// blocks >= SCAN_G: build WcT (128x384 bf16): k<128: W1-W3; k<256: -W2; else 2*W3.
__global__ __launch_bounds__(512) void scan_final(const int* __restrict__ cnt,
                                                  const int* __restrict__ part,
                                                  int* __restrict__ off,
                                                  const float* __restrict__ W1,
                                                  const float* __restrict__ W2,
                                                  const float* __restrict__ W3,
                                                  ushort_t* __restrict__ wcT) {
    if (blockIdx.x >= SCAN_G) {
        int i = (blockIdx.x - SCAN_G) * 512 + threadIdx.x;   // 96*512 = 49152 = 128*384
        int d = i / 384, k = i % 384;
        float v;
        if (k < 128)      v = W1[k * DD + d] - W3[k * DD + d];
        else if (k < 256) v = -W2[(k - 128) * DD + d];
        else              v = 2.0f * W3[(k - 256) * DD + d];
        wcT[i] = f2b(v);
        return;
    }
    __shared__ int wsum[8];
    __shared__ int sbase;
    int t = threadIdx.x;
    int lane = t & 63, wv = t >> 6;

    int p = (t < blockIdx.x && t < SCAN_G) ? part[t] : 0;
    #pragma unroll
    for (int s = 1; s < 64; s <<= 1) p += __shfl_xor(p, s);
    if (lane == 0) wsum[wv] = p;
    __syncthreads();
    if (t == 0) {
        int b = 0;
        #pragma unroll
        for (int k = 0; k < 8; ++k) b += wsum[k];
        sbase = b;
    }
    __syncthreads();

    int i = blockIdx.x * 512 + t;
    int v = (i < NN) ? cnt[i] : 0;
    int incl = v;
    #pragma unroll
    for (int s = 1; s < 64; s <<= 1) {
        int u = __shfl_up(incl, s);
        if (lane >= s) incl += u;
    }
    __syncthreads();
    if (lane == 63) wsum[wv] = incl;
    __syncthreads();
    int woff = 0;
    for (int k = 0; k < wv; ++k) woff += wsum[k];
    int excl = sbase + woff + incl - v;
    if (i < NN) off[i] = excl;
    if (blockIdx.x == 0 && t == 0) off[NN] = NE;
}

// csr[off[dst]+epos] = (src, bits(norm[src])) — atomic-free scatter
__global__ void fill_kernel(const int* __restrict__ src, const int* __restrict__ dst,
                            const int* __restrict__ epos, const int* __restrict__ off,
                            const float* __restrict__ norm, int2* __restrict__ csr) {
    int e = blockIdx.x * 256 + threadIdx.x;
    if (e >= NE) return;
    int s = src[e];
    int p = off[dst[e]] + epos[e];
    csr[p] = make_int2(s, __float_as_int(norm[s]));
}

// ---------- message passing (bf16 in, bf16 out) ----------
// QUARTER-WAVE (16 lanes) per NODE; lane covers 8 cols (uint4 = 16B).
// 4-deep unroll => 4 independent row loads per group, 16 per wave, sustained.
__global__ __launch_bounds__(256) void gather_bf(const ushort_t* __restrict__ x,
                                                 const float* __restrict__ norm,
                                                 const int* __restrict__ off,
                                                 const int2* __restrict__ csr,
                                                 ushort_t* __restrict__ out) {
    int g = (blockIdx.x << 4) | (threadIdx.x >> 4);   // node id; 3125*16 = 50000
    int l4 = threadIdx.x & 15;
    int jb = off[g], je = off[g + 1];
    const uint4* xp = reinterpret_cast<const uint4*>(x);   // row = 16 x uint4
    float a0 = 0.f, a1 = 0.f, a2 = 0.f, a3 = 0.f;
    float a4 = 0.f, a5 = 0.f, a6 = 0.f, a7 = 0.f;

#define ACC(cc, vv)                                                  \
    {                                                                \
        float n_ = __int_as_float(cc.y);                             \
        a0 = fmaf(n_, b2f((ushort_t)(vv.x)), a0);                    \
        a1 = fmaf(n_, b2f((ushort_t)(vv.x >> 16)), a1);              \
        a2 = fmaf(n_, b2f((ushort_t)(vv.y)), a2);                    \
        a3 = fmaf(n_, b2f((ushort_t)(vv.y >> 16)), a3);              \
        a4 = fmaf(n_, b2f((ushort_t)(vv.z)), a4);                    \
        a5 = fmaf(n_, b2f((ushort_t)(vv.z >> 16)), a5);              \
        a6 = fmaf(n_, b2f((ushort_t)(vv.w)), a6);                    \
        a7 = fmaf(n_, b2f((ushort_t)(vv.w >> 16)), a7);              \
    }

    int j = jb;
    for (; j + 4 <= je; j += 4) {
        int2 c0 = csr[j + 0];
        int2 c1 = csr[j + 1];
        int2 c2 = csr[j + 2];
        int2 c3 = csr[j + 3];
        uint4 v0 = xp[(size_t)c0.x * 16 + l4];
        uint4 v1 = xp[(size_t)c1.x * 16 + l4];
        uint4 v2 = xp[(size_t)c2.x * 16 + l4];
        uint4 v3 = xp[(size_t)c3.x * 16 + l4];
        ACC(c0, v0); ACC(c1, v1); ACC(c2, v2); ACC(c3, v3);
    }
    for (; j < je; ++j) {
        int2 c = csr[j];
        uint4 v = xp[(size_t)c.x * 16 + l4];
        ACC(c, v);
    }
#undef ACC

    float nd = norm[g];
    uint4 o;
    o.x = (uint_t)f2b(nd * a0) | ((uint_t)f2b(nd * a1) << 16);
    o.y = (uint_t)f2b(nd * a2) | ((uint_t)f2b(nd * a3) << 16);
    o.z = (uint_t)f2b(nd * a4) | ((uint_t)f2b(nd * a5) << 16);
    o.w = (uint_t)f2b(nd * a6) | ((uint_t)f2b(nd * a7) << 16);
    reinterpret_cast<uint4*>(out)[(size_t)g * 16 + l4] = o;
}

// ---------- MFMA GEMM + BN partials ----------
// 128-row blocks, 4 waves; wave owns 32 rows x 128 cols (2 row-groups).
__global__ __launch_bounds__(256) void gemm_bn(
    const ushort_t* __restrict__ feat_bf, const ushort_t* __restrict__ ax_bf,
    const ushort_t* __restrict__ ax2_bf, const ushort_t* __restrict__ wcT,
    const float* __restrict__ bias, const float* __restrict__ snorm,
    ushort_t* __restrict__ t_out, float* __restrict__ gsums, float* __restrict__ gsq)
{
    __shared__ ushort_t As[128 * 128];   // 32 KB, XOR-swizzled
    __shared__ ushort_t Bs[128 * 128];   // 32 KB, XOR-swizzled
    int tid = threadIdx.x;
    int w = tid >> 6, lane = tid & 63;
    int row0 = blockIdx.x * 128;

    f32x4 acc[2][8] = {};

    #pragma unroll
    for (int kt = 0; kt < 3; ++kt) {
        const ushort_t* S = (kt == 0) ? feat_bf : (kt == 1) ? ax_bf : ax2_bf;
        __syncthreads();
        {
            int r = tid >> 1, hh = tid & 1;
            int grow = min(row0 + r, NN - 1);
            const char* gsrc = (const char*)(S + grow * DD);
            char* dbase = (char*)As + r * 256;
            int sw = (r & 7) << 4;
            #pragma unroll
            for (int c = 0; c < 8; ++c) {
                int cb = hh * 128 + c * 16;
                *(short8v*)(dbase + (cb ^ sw)) = *(const short8v*)(gsrc + cb);
            }
        }
        {
            int cidx = tid >> 1, hh = tid & 1;
            const char* gsrc = (const char*)(wcT + cidx * 384 + kt * 128);
            char* dbase = (char*)Bs + cidx * 256;
            int sw = (cidx & 7) << 4;
            #pragma unroll
            for (int c = 0; c < 8; ++c) {
                int cb = hh * 128 + c * 16;
                *(short8v*)(dbase + (cb ^ sw)) = *(const short8v*)(gsrc + cb);
            }
        }
        __syncthreads();
        int l15 = lane & 15;
        int r0a = w * 32 + l15;
        int r1a = r0a + 16;
        #pragma unroll
        for (int ks = 0; ks < 4; ++ks) {
            int kb = ks * 64 + ((lane >> 4) << 4);
            short8v a0 = *(const short8v*)((const char*)As + r0a * 256 + (kb ^ ((r0a & 7) << 4)));
            short8v a1 = *(const short8v*)((const char*)As + r1a * 256 + (kb ^ ((r1a & 7) << 4)));
            #pragma unroll
            for (int cf = 0; cf < 8; ++cf) {
                int col = cf * 16 + l15;
                short8v b = *(const short8v*)((const char*)Bs + col * 256 + (kb ^ ((col & 7) << 4)));
                acc[0][cf] = __builtin_amdgcn_mfma_f32_16x16x32_bf16(a0, b, acc[0][cf], 0, 0, 0);
                acc[1][cf] = __builtin_amdgcn_mfma_f32_16x16x32_bf16(a1, b, acc[1][cf], 0, 0, 0);
            }
        }
    }

    int q = lane >> 4, c0 = lane & 15;
    float s1[8], s2[8];
    #pragma unroll
    for (int cf = 0; cf < 8; ++cf) { s1[cf] = 0.f; s2[cf] = 0.f; }

    #pragma unroll
    for (int g = 0; g < 2; ++g) {
        int rbase = row0 + w * 32 + g * 16 + q * 4;
        float sn[4];
        #pragma unroll
        for (int i = 0; i < 4; ++i) sn[i] = (rbase + i < NN) ? snorm[rbase + i] : 0.f;
        #pragma unroll
        for (int cf = 0; cf < 8; ++cf) {
            int col = cf * 16 + c0;
            float bc = bias[col];
            #pragma unroll
            for (int i = 0; i < 4; ++i) {
                int row = rbase + i;
                if (row < NN) {
                    float t = (acc[g][cf][i] + bc) * sn[i];
                    t_out[row * DD + col] = f2b(t);
                    s1[cf] += t; s2[cf] += t * t;
                }
            }
        }
    }
    #pragma unroll
    for (int cf = 0; cf < 8; ++cf) {
        s1[cf] += __shfl_xor(s1[cf], 16); s1[cf] += __shfl_xor(s1[cf], 32);
        s2[cf] += __shfl_xor(s2[cf], 16); s2[cf] += __shfl_xor(s2[cf], 32);
    }
    if (q == 0) {
        int slot = (blockIdx.x & 31) * DD;
        #pragma unroll
        for (int cf = 0; cf < 8; ++cf) {
            atomAdd(&gsums[slot + cf * 16 + c0], s1[cf]);
            atomAdd(&gsq[slot + cf * 16 + c0], s2[cf]);
        }
    }
}

__global__ void bn_finalize(const float* __restrict__ gsums, const float* __restrict__ gsq,
                            const float* __restrict__ gamma,
                            const float* __restrict__ beta,
                            float* __restrict__ scale, float* __restrict__ shift) {
    int d = threadIdx.x;  // 128
    float s1 = 0.f, s2 = 0.f;
    for (int c = 0; c < 32; ++c) { s1 += gsums[c * DD + d]; s2 += gsq[c * DD + d]; }
    float mean = s1 / (float)NN;
    float var  = s2 / (float)NN - mean * mean;
    float sc = gamma[d] * rsqrtf(var + BN_EPS);
    scale[d] = sc;
    shift[d] = beta[d] - mean * sc;
}

// out = feat_bf + relu(t*scale + shift)   (both bf16 inputs, f32 out)
__global__ void epilogue(const ushort_t* __restrict__ t, const ushort_t* __restrict__ featb,
                         const float* __restrict__ scale, const float* __restrict__ shift,
                         float* __restrict__ out) {
    int i = blockIdx.x * 256 + threadIdx.x;
    if (i >= NN * DD / 4) return;
    int d0 = (i << 2) & 127;
    ushort4 tv = reinterpret_cast<const ushort4*>(t)[i];
    ushort4 fv = reinterpret_cast<const ushort4*>(featb)[i];
    float4 o;
    o.x = b2f(fv.x) + fmaxf(b2f(tv.x) * scale[d0 + 0] + shift[d0 + 0], 0.f);
    o.y = b2f(fv.y) + fmaxf(b2f(tv.y) * scale[d0 + 1] + shift[d0 + 1], 0.f);
    o.z = b2f(fv.z) + fmaxf(b2f(tv.z) * scale[d0 + 2] + shift[d0 + 2], 0.f);
    o.w = b2f(fv.w) + fmaxf(b2f(tv.w) * scale[d0 + 3] + shift[d0 + 3], 0.f);
    reinterpret_cast<float4*>(out)[i] = o;
}

extern "C" void kernel_launch(void* const* d_in, const int* in_sizes, int n_in,
                              void* d_out, int out_size, void* d_ws, size_t ws_size,
                              hipStream_t stream) {
    const float* feat  = (const float*)d_in[0];
    const float* snorm = (const float*)d_in[1];
    const float* W1    = (const float*)d_in[2];
    const float* W2    = (const float*)d_in[3];
    const float* W3    = (const float*)d_in[4];
    const float* bias  = (const float*)d_in[5];
    const float* gamma = (const float*)d_in[6];
    const float* beta  = (const float*)d_in[7];
    const int* esrc = (const int*)d_in[8];
    const int* edst = (const int*)d_in[9];
    float* out = (float*)d_out;

    char* ws = (char*)d_ws;
    ushort_t* t_bf    = (ushort_t*)(ws);                 // 12,800,000 (gemm output)
    int*      epos    = (int*)     (ws);                 //  3,200,000 ALIAS of t_bf
                                                         //  (epos dead before gemm_bn runs)
    ushort_t* feat_bf = (ushort_t*)(ws + 12800000);      // 12,800,000
    ushort_t* ax_bf   = (ushort_t*)(ws + 25600000);      // 12,800,000
    ushort_t* ax2_bf  = (ushort_t*)(ws + 38400000);      // 12,800,000
    int2*     csr     = (int2*)    (ws + 51200000);      //  6,400,000 (src, norm bits)
    float*    norm    = (float*)   (ws + 57600000);      //    200,000
    int*      cnt     = (int*)     (ws + 57800000);      //    200,000 (-> deg)
    float*    gsums   = (float*)   (ws + 58000000);      //     16,384
    float*    gsq     = (float*)   (ws + 58016384);      //     16,384
    int*      off     = (int*)     (ws + 58032768);      //    200,064
    int*      part    = (int*)     (ws + 58232832);      //        512
    float*    scale   = (float*)   (ws + 58233856);      //        512
    float*    shift   = (float*)   (ws + 58234368);      //        512
    ushort_t* wcT     = (ushort_t*)(ws + 58234880);      //     98,304 (end 58,333,184)

    hipMemsetAsync(ws + 57800000, 0, 200000, stream);    // cnt only

    epos_prep  <<<3125, 256, 0, stream>>>(edst, cnt, epos, feat, feat_bf,
                                          (float4*)(ws + 58000000));
    scan_part  <<<SCAN_G, 512, 0, stream>>>(cnt, part, norm);
    scan_final <<<SCAN_G + 96, 512, 0, stream>>>(cnt, part, off, W1, W2, W3, wcT);
    fill_kernel<<<3125, 256, 0, stream>>>(esrc, edst, epos, off, norm, csr);

    gather_bf<<<3125, 256, 0, stream>>>(feat_bf, norm, off, csr, ax_bf);
    gather_bf<<<3125, 256, 0, stream>>>(ax_bf,   norm, off, csr, ax2_bf);

    gemm_bn<<<391, 256, 0, stream>>>(feat_bf, ax_bf, ax2_bf, wcT, bias, snorm,
                                     t_bf, gsums, gsq);
    bn_finalize<<<1, 128, 0, stream>>>(gsums, gsq, gamma, beta, scale, shift);
    epilogue   <<<6250, 256, 0, stream>>>(t_bf, feat_bf, scale, shift, out);
}